// Round 9
// baseline (22.216 us; speedup 1.0000x reference)
//
#include <hip/hip_runtime.h>

typedef float f32x2 __attribute__((ext_vector_type(2)));

// Problem constants (fixed by the reference)
#define C8     8      // feat channels
#define KOBJ   32     // objects per image
#define BIMG   8      // batch
#define WW     128
#define HWPIX  16384  // H*W
#define CWN    169    // conv params per object
#define PIX    8      // contiguous pixels per thread (2 batches of 4)
#define GRIDX  8      // tiles per (b,k)
#define SLOTS_PER_B (KOBJ * GRIDX)      // 256 slots per image
#define NBLK   (BIMG * KOBJ * GRIDX)    // 2048 blocks / slots

// D = S0*S1 + D  (packed 2x fp32 FMA, IEEE-identical to fmaf)
__device__ __forceinline__ void pkfma(f32x2& d, f32x2 a, f32x2 b) {
    asm("v_pk_fma_f32 %0, %1, %2, %0" : "+v"(d) : "v"(a), "v"(b));
}

__global__ __launch_bounds__(256) void mask_head_kernel(
    const float* __restrict__ seg_feat,    // [B,8,H,W]
    const float* __restrict__ conv_weight, // [B,169,H,W]
    const int* __restrict__ mask,          // [B,K]
    const long long* __restrict__ ind,     // [B,K]
    const float* __restrict__ target,      // [B,K,H,W]
    float* __restrict__ partial)           // [NBLK][3]
{
    const int tile = blockIdx.x;
    const int k    = blockIdx.y;
    const int b    = blockIdx.z;
    const int t    = threadIdx.x;
    const int pair = b * KOBJ + k;
    const int slot = pair * GRIDX + tile;

    // Duplicated weights ({w,w}) so one ds_read_b64 yields a pk broadcast.
    __shared__ f32x2 wd1[C8][10];   // [o][c]: c 0..7 seg, 8 = wx, 9 = wy
    __shared__ f32x2 l1b2[C8];
    __shared__ f32x2 wd2[C8][C8];
    __shared__ f32x2 l2b2[C8];
    __shared__ f32x2 w3d[C8];
    __shared__ float b3s;
    __shared__ float red[4][3];

    // Parallel independent loads: mask and ind issue together (one HBM round).
    const int       mval  = mask[pair];
    const long long idxll = ind[pair];
    if (mval == 0) {                        // masked: exact zero, cheap exit
        if (t < 3) partial[slot * 3 + t] = 0.f;
        return;
    }
    const int idx = (int)idxll;

    // Issue the weight gather first...
    float gv = 0.f;
    if (t < CWN) gv = conv_weight[(b * CWN + t) * HWPIX + idx];

    const float* seg = seg_feat + b * C8 * HWPIX;
    const float* tgt = target + pair * HWPIX;
    const int p0   = tile * 2048 + t * PIX;   // 8 contiguous px, same row
    const int row  = p0 >> 7;
    const int col0 = p0 & (WW - 1);

    // ...then prefetch target + first-half seg BEFORE the barrier: these
    // loads complete during the gather->LDS->barrier stall for free.
    const float4 tA = *reinterpret_cast<const float4*>(&tgt[p0]);
    const float4 tB = *reinterpret_cast<const float4*>(&tgt[p0 + 4]);
    float4 s0[C8];
#pragma unroll
    for (int c = 0; c < C8; ++c)
        s0[c] = *reinterpret_cast<const float4*>(&seg[c * HWPIX + p0]);

    // gather -> LDS (duplicated); ds_write waits only on the gather load
    if (t < CWN) {
        const f32x2 v2 = {gv, gv};
        if (t < 80)       { wd1[t / 10][t % 10] = v2; }
        else if (t < 88)  { l1b2[t - 80] = v2; }
        else if (t < 152) { const int u = t - 88; wd2[u >> 3][u & 7] = v2; }
        else if (t < 160) { l2b2[t - 152] = v2; }
        else if (t < 168) { w3d[t - 160] = v2; }
        else              { b3s = gv; }
    }
    __syncthreads();

    const float cx = (float)(idx & (WW - 1));
    const float cy = (float)(idx >> 7);
    const float sy = ((float)row - cy) * (1.0f / 128.0f);
    const f32x2 sy2 = {sy, sy};

    float s_pt = 0.f, s_pp = 0.f, s_tt = 0.f;

    // ================= half 0 (px 0..3) =================
    const float colq0 = (float)col0;
    f32x2 sxa = {(colq0 - cx) * (1.0f / 128.0f), (colq0 + 1.0f - cx) * (1.0f / 128.0f)};
    f32x2 sxb = {(colq0 + 2.0f - cx) * (1.0f / 128.0f), (colq0 + 3.0f - cx) * (1.0f / 128.0f)};

    f32x2 h1[C8][2];
#pragma unroll
    for (int o = 0; o < C8; ++o) {
        f32x2 base2 = l1b2[o];
        pkfma(base2, wd1[o][9], sy2);
        f32x2 acc0 = base2, acc1 = base2;
        pkfma(acc0, wd1[o][8], sxa);
        pkfma(acc1, wd1[o][8], sxb);
#pragma unroll
        for (int c = 0; c < C8; ++c) {
            const f32x2 w = wd1[o][c];
            const f32x2 f0 = {s0[c].x, s0[c].y};
            const f32x2 f1 = {s0[c].z, s0[c].w};
            pkfma(acc0, w, f0);
            pkfma(acc1, w, f1);
        }
        h1[o][0] = {fmaxf(acc0.x, 0.f), fmaxf(acc0.y, 0.f)};
        h1[o][1] = {fmaxf(acc1.x, 0.f), fmaxf(acc1.y, 0.f)};
    }

    // issue second-half seg loads here: overlap with layers 2+3 compute
    float4 s1[C8];
#pragma unroll
    for (int c = 0; c < C8; ++c)
        s1[c] = *reinterpret_cast<const float4*>(&seg[c * HWPIX + p0 + 4]);

    {
        f32x2 z0 = {b3s, b3s}, z1 = z0;
#pragma unroll
        for (int o = 0; o < C8; ++o) {
            f32x2 acc0 = l2b2[o], acc1 = l2b2[o];
#pragma unroll
            for (int c = 0; c < C8; ++c) {
                const f32x2 w = wd2[o][c];
                pkfma(acc0, w, h1[c][0]);
                pkfma(acc1, w, h1[c][1]);
            }
            const f32x2 r0 = {fmaxf(acc0.x, 0.f), fmaxf(acc0.y, 0.f)};
            const f32x2 r1 = {fmaxf(acc1.x, 0.f), fmaxf(acc1.y, 0.f)};
            const f32x2 w3 = w3d[o];
            pkfma(z0, w3, r0);
            pkfma(z1, w3, r1);
        }
        const float zz[4] = {z0.x, z0.y, z1.x, z1.y};
        const float tv[4] = {tA.x, tA.y, tA.z, tA.w};
#pragma unroll
        for (int i = 0; i < 4; ++i) {
            const float e    = __expf(-zz[i]);
            const float pred = __builtin_amdgcn_rcpf(1.0f + e);
            s_pt = fmaf(pred, tv[i], s_pt);
            s_pp = fmaf(pred, pred, s_pp);
            s_tt = fmaf(tv[i], tv[i], s_tt);
        }
    }

    // ================= half 1 (px 4..7) =================
    const float colq1 = (float)(col0 + 4);
    sxa = {(colq1 - cx) * (1.0f / 128.0f), (colq1 + 1.0f - cx) * (1.0f / 128.0f)};
    sxb = {(colq1 + 2.0f - cx) * (1.0f / 128.0f), (colq1 + 3.0f - cx) * (1.0f / 128.0f)};

#pragma unroll
    for (int o = 0; o < C8; ++o) {
        f32x2 base2 = l1b2[o];
        pkfma(base2, wd1[o][9], sy2);
        f32x2 acc0 = base2, acc1 = base2;
        pkfma(acc0, wd1[o][8], sxa);
        pkfma(acc1, wd1[o][8], sxb);
#pragma unroll
        for (int c = 0; c < C8; ++c) {
            const f32x2 w = wd1[o][c];
            const f32x2 f0 = {s1[c].x, s1[c].y};
            const f32x2 f1 = {s1[c].z, s1[c].w};
            pkfma(acc0, w, f0);
            pkfma(acc1, w, f1);
        }
        h1[o][0] = {fmaxf(acc0.x, 0.f), fmaxf(acc0.y, 0.f)};
        h1[o][1] = {fmaxf(acc1.x, 0.f), fmaxf(acc1.y, 0.f)};
    }
    {
        f32x2 z0 = {b3s, b3s}, z1 = z0;
#pragma unroll
        for (int o = 0; o < C8; ++o) {
            f32x2 acc0 = l2b2[o], acc1 = l2b2[o];
#pragma unroll
            for (int c = 0; c < C8; ++c) {
                const f32x2 w = wd2[o][c];
                pkfma(acc0, w, h1[c][0]);
                pkfma(acc1, w, h1[c][1]);
            }
            const f32x2 r0 = {fmaxf(acc0.x, 0.f), fmaxf(acc0.y, 0.f)};
            const f32x2 r1 = {fmaxf(acc1.x, 0.f), fmaxf(acc1.y, 0.f)};
            const f32x2 w3 = w3d[o];
            pkfma(z0, w3, r0);
            pkfma(z1, w3, r1);
        }
        const float zz[4] = {z0.x, z0.y, z1.x, z1.y};
        const float tv[4] = {tB.x, tB.y, tB.z, tB.w};
#pragma unroll
        for (int i = 0; i < 4; ++i) {
            const float e    = __expf(-zz[i]);
            const float pred = __builtin_amdgcn_rcpf(1.0f + e);
            s_pt = fmaf(pred, tv[i], s_pt);
            s_pp = fmaf(pred, pred, s_pp);
            s_tt = fmaf(tv[i], tv[i], s_tt);
        }
    }

    // wave reduction, then block reduction via LDS
#pragma unroll
    for (int off = 32; off > 0; off >>= 1) {
        s_pt += __shfl_down(s_pt, off);
        s_pp += __shfl_down(s_pp, off);
        s_tt += __shfl_down(s_tt, off);
    }
    const int wid = t >> 6;
    if ((t & 63) == 0) { red[wid][0] = s_pt; red[wid][1] = s_pp; red[wid][2] = s_tt; }
    __syncthreads();
    if (t == 0) {
        float a = 0.f, b2 = 0.f, c2 = 0.f;
#pragma unroll
        for (int i = 0; i < 4; ++i) { a += red[i][0]; b2 += red[i][1]; c2 += red[i][2]; }
        partial[slot * 3 + 0] = a;
        partial[slot * 3 + 1] = b2;
        partial[slot * 3 + 2] = c2;
    }
}

__global__ __launch_bounds__(512) void finalize_kernel(
    const float* __restrict__ partial, float* __restrict__ out)
{
    const int t    = threadIdx.x;
    const int b    = t >> 6;   // one wave per image
    const int lane = t & 63;

    float pt = 0.f, pp = 0.f, tt = 0.f;
    for (int e = lane; e < SLOTS_PER_B; e += 64) {
        const float* q = partial + (b * SLOTS_PER_B + e) * 3;
        pt += q[0]; pp += q[1]; tt += q[2];
    }
#pragma unroll
    for (int off = 32; off > 0; off >>= 1) {
        pt += __shfl_down(pt, off);
        pp += __shfl_down(pp, off);
        tt += __shfl_down(tt, off);
    }
    __shared__ float per[BIMG];
    if (lane == 0) {
        per[b] = 1.0f - (2.0f * pt + 1.0f) / (pp + tt + 1.0f);
    }
    __syncthreads();
    if (t == 0) {
        float s = 0.f;
#pragma unroll
        for (int i = 0; i < BIMG; ++i) s += per[i];
        out[0] = s * (1.0f / (float)BIMG);
    }
}

extern "C" void kernel_launch(void* const* d_in, const int* in_sizes, int n_in,
                              void* d_out, int out_size, void* d_ws, size_t ws_size,
                              hipStream_t stream) {
    const float*     seg  = (const float*)d_in[0];
    const float*     cw   = (const float*)d_in[1];
    const int*       mask = (const int*)d_in[2];
    const long long* ind  = (const long long*)d_in[3];
    const float*     tgt  = (const float*)d_in[4];
    float* out     = (float*)d_out;
    float* partial = (float*)d_ws;   // NBLK*3 floats = 24 KiB

    mask_head_kernel<<<dim3(GRIDX, KOBJ, BIMG), 256, 0, stream>>>(
        seg, cw, mask, ind, tgt, partial);
    finalize_kernel<<<1, 512, 0, stream>>>(partial, out);
}